// Round 7
// baseline (24842.230 us; speedup 1.0000x reference)
//
#include <hip/hip_runtime.h>
#include <cstdint>
#include <cstddef>

#define T_LEN 2048
#define B_SZ 4
#define C_CH 512
#define H_N 8
#define DK_ 64
#define FC_CH 2048
#define L_N 6
#define KW 3
#define S_CH 256

typedef _Float16 h8 __attribute__((ext_vector_type(8)));
typedef _Float16 h4 __attribute__((ext_vector_type(4)));
typedef float floatx4 __attribute__((ext_vector_type(4)));

// ---------------------------------------------------------------------------
// Weight prepack kernels (run every call; weights -> f16 in ws).
// ---------------------------------------------------------------------------
__global__ __launch_bounds__(256)
void cast_f16(const float* __restrict__ src, _Float16* __restrict__ dst, int n)
{
    int i = blockIdx.x * 256 + threadIdx.x;
    if (i < n) dst[i] = (_Float16)src[i];
}

// src [row][c][k] (k fastest, K=3) -> dst [row][c0blk][k][cl] (32-ch chunks)
__global__ __launch_bounds__(256)
void prepack_k3(const float* __restrict__ src, _Float16* __restrict__ dst,
                int Cin, int total)
{
    int i = blockIdx.x * 256 + threadIdx.x;
    if (i >= total) return;
    const int rk = Cin * 3;
    int row = i / rk, o = i - row * rk;
    int blk = o / 96, rr = o - blk * 96;
    int k = rr >> 5, cl = rr & 31;
    dst[i] = (_Float16)src[(size_t)row * rk + (size_t)(blk * 32 + cl) * 3 + k];
}

// concat q|k|v weights into [l][1536][512] f16 + biases into [l][1536] f32
__global__ __launch_bounds__(256)
void prepack_qkv(const float* __restrict__ qw, const float* __restrict__ kw,
                 const float* __restrict__ vw, const float* __restrict__ qb,
                 const float* __restrict__ kb, const float* __restrict__ vb,
                 _Float16* __restrict__ dst, float* __restrict__ bdst)
{
    int i = blockIdx.x * 256 + threadIdx.x;
    const int total = L_N * 1536 * 512;
    if (i < total) {
        int l = i / (1536 * 512);
        int o = i - l * (1536 * 512);
        int m = o >> 9, c = o & 511;
        const float* s = (m < 512) ? qw : ((m < 1024) ? kw : vw);
        dst[i] = (_Float16)s[((size_t)l * 512 + (m & 511)) * 512 + c];
    }
    if (i < L_N * 1536) {
        int l = i / 1536, m = i - l * 1536;
        const float* s = (m < 512) ? qb : ((m < 1024) ? kb : vb);
        bdst[i] = s[l * 512 + (m & 511)];
    }
}

// ---------------------------------------------------------------------------
// Transpose [b][Cd][T] -> f16 [b][T][Cd], optionally fusing the f0 conv add.
// ---------------------------------------------------------------------------
__global__ __launch_bounds__(256)
void transpose_f0(const float* __restrict__ src, _Float16* __restrict__ dst, int Cd,
                  const float* __restrict__ nf0, const float* __restrict__ f0w,
                  const float* __restrict__ f0b, int do_f0)
{
    __shared__ float tile[32][33];
    const int tl = threadIdx.x & 31;
    const int r  = threadIdx.x >> 5;
    const int t00 = blockIdx.x * 32;
    const int c00 = blockIdx.y * 32;
    const int b   = blockIdx.z;
    const float* s0 = src + (size_t)b * Cd * T_LEN;
#pragma unroll
    for (int rr = 0; rr < 4; ++rr) {
        int cl = r + rr * 8;
        tile[cl][tl] = s0[(size_t)(c00 + cl) * T_LEN + t00 + tl];
    }
    __syncthreads();
    _Float16* d0 = dst + (size_t)b * T_LEN * Cd;
    const int cg = c00 + tl;
#pragma unroll
    for (int rr = 0; rr < 4; ++rr) {
        int tlo = r + rr * 8;
        float v = tile[tl][tlo];
        if (do_f0) {
            int tg = t00 + tlo;
            float a = f0b[cg];
#pragma unroll
            for (int k = 0; k < 3; ++k) {
                int gt = tg + k - 1;
                if (gt >= 0 && gt < T_LEN) a += f0w[cg * 3 + k] * nf0[(size_t)b * T_LEN + gt];
            }
            v += a;
        }
        d0[(size_t)(t00 + tlo) * Cd + cg] = (_Float16)v;
    }
}

// ---------------------------------------------------------------------------
// Conv1d-as-GEMM on MFMA, prepacked f16 weights, f16 activations.
// Pipelining: A 1-deep register prefetch (L2-resident weights, ~200cyc),
// B 2-deep register double-buffer (HBM activations, ~900cyc).
// LDS staging patterns chosen so each 8-lane phase hits 8 distinct bank-quads
// (KK=3: A row=tid&127 @52-word stride; B row=id%132 @20-word stride;
//  KK=1 legacy patterns verified conflict-free at 36-word stride).
// OUTMODE: 1 = f16 [b][t][out_stride] (+res); 3 = fused QKV (m0<1024 -> out_v
// stride 1024; m0>=1024 -> out2 transposed [b][m-1024][t]).
// ---------------------------------------------------------------------------
template<int KK, int OUTMODE>
__global__ __launch_bounds__(256)
void conv_gemm_mfma(const _Float16* __restrict__ in, const _Float16* __restrict__ Wpk,
                    const float* __restrict__ bias, const _Float16* __restrict__ res,
                    const float* __restrict__ mask, _Float16* __restrict__ out_v,
                    _Float16* __restrict__ out2,
                    int Cin, int out_stride, int pl, int do_relu,
                    int mask_in, int mask_out)
{
    constexpr int CS   = (KK == 3) ? 32 : 64;   // channels per chunk
    constexpr int NSEC = (KK == 3) ? 3 : 2;     // 32-wide A sections
    constexpr int AST  = NSEC * 32 + 8;         // 104 / 72 halves
    constexpr int HALO = (KK == 3) ? 2 : 0;
    constexpr int RB   = 128 + 2 * HALO;
    constexpr int BST  = CS + 8;                // 40 / 72 halves
    constexpr int NAH  = NSEC * 2;              // A h8-regs per thread
    constexpr int NTASK = RB * (CS / 16);       // B 16-half tasks (264 / 512)
    __shared__ _Float16 sA[128 * AST];
    __shared__ _Float16 sB[RB * BST];

    const int tid = threadIdx.x;
    const int lane = tid & 63;
    const int wid = tid >> 6;
    const int wm = wid >> 1, wt = wid & 1;
    const int r = lane & 15, q4 = lane >> 4;
    const int t0 = blockIdx.x * 128;
    const int m0 = blockIdx.y * 128;
    const int b  = blockIdx.z;
    const float* mk = mask + (size_t)b * T_LEN;

    floatx4 acc[4][4];
#pragma unroll
    for (int i = 0; i < 4; ++i)
#pragma unroll
        for (int j = 0; j < 4; ++j)
#pragma unroll
            for (int c = 0; c < 4; ++c) acc[i][j][c] = 0.f;

    // ---- A staging assignment (bank-conflict-free writes) ----
    const int arow = (KK == 3) ? (tid & 127) : (tid >> 1);
    const int ah0  = (KK == 3) ? ((tid >> 7) * (NSEC * 16)) : ((tid & 1) * (NSEC * 16));
    const _Float16* ap = Wpk + (size_t)(m0 + arow) * Cin * KK + ah0;

    // ---- B task decode (chunk-invariant) ----
    int brw[2], bcc[2];
    bool bex[2], bval[2];
    _Float16 bm[2];
    const _Float16* bq[2];
    h8 areg[NAH], breg[2][2][2];   // breg[buf][task][half]
#pragma unroll
    for (int t2 = 0; t2 < 2; ++t2) {
        const int id = tid + t2 * 256;
        bex[t2] = (id < NTASK);
        int row, c16;
        if (KK == 3) { row = id % RB; c16 = (id / RB) * 16; }
        else         { row = id >> 2; c16 = (id & 3) * 16; }
        const int gt = t0 + row - HALO;
        bval[t2] = bex[t2] && gt >= 0 && gt < T_LEN;
        brw[t2] = row; bcc[t2] = c16;
        bm[t2] = (_Float16)((bval[t2] && mask_in) ? mk[gt] : 1.f);
        bq[t2] = in + (size_t)b * T_LEN * Cin + (size_t)gt * Cin + c16;
#pragma unroll
        for (int d = 0; d < 2; ++d)
#pragma unroll
            for (int hh = 0; hh < 2; ++hh)
#pragma unroll
                for (int j = 0; j < 8; ++j) breg[d][t2][hh][j] = (_Float16)0.f;
    }
    const int nch = Cin / CS;
    // ---- prologue: A chunk 0, B chunks 0 and 1 ----
#pragma unroll
    for (int j = 0; j < NAH; ++j) areg[j] = *reinterpret_cast<const h8*>(ap + j * 8);
#pragma unroll
    for (int d = 0; d < 2; ++d)
#pragma unroll
        for (int t2 = 0; t2 < 2; ++t2)
            if (bval[t2]) {
                breg[d][t2][0] = *reinterpret_cast<const h8*>(bq[t2] + d * CS);
                breg[d][t2][1] = *reinterpret_cast<const h8*>(bq[t2] + d * CS + 8);
            }
#pragma unroll
    for (int t2 = 0; t2 < 2; ++t2) bq[t2] += 2 * CS;   // next B load target

    for (int ci = 0; ci < nch; ++ci) {
        const int buf = ci & 1;
        __syncthreads();                     // LDS consumers of chunk ci-1 done
        // ---- regs -> LDS ----
#pragma unroll
        for (int j = 0; j < NAH; ++j)
            *reinterpret_cast<h8*>(&sA[arow * AST + ah0 + j * 8]) = areg[j];
#pragma unroll
        for (int t2 = 0; t2 < 2; ++t2)
            if (bex[t2]) {
                *reinterpret_cast<h8*>(&sB[brw[t2] * BST + bcc[t2]]) = breg[buf][t2][0] * bm[t2];
                *reinterpret_cast<h8*>(&sB[brw[t2] * BST + bcc[t2] + 8]) = breg[buf][t2][1] * bm[t2];
            }
        __syncthreads();
        // ---- issue prefetches (overlap with MFMAs below) ----
        if (ci + 1 < nch) {
            ap += CS * KK;
#pragma unroll
            for (int j = 0; j < NAH; ++j) areg[j] = *reinterpret_cast<const h8*>(ap + j * 8);
        }
        if (ci + 2 < nch) {
#pragma unroll
            for (int t2 = 0; t2 < 2; ++t2)
                if (bval[t2]) {
                    breg[buf][t2][0] = *reinterpret_cast<const h8*>(bq[t2]);
                    breg[buf][t2][1] = *reinterpret_cast<const h8*>(bq[t2] + 8);
                    bq[t2] += CS;
                }
        }
        // ---- NSEC sections x 16 MFMA ----
#pragma unroll
        for (int sec = 0; sec < NSEC; ++sec) {
            h8 af[4], bf[4];
#pragma unroll
            for (int im = 0; im < 4; ++im)
                af[im] = *reinterpret_cast<const h8*>(&sA[(wm * 64 + im * 16 + r) * AST + sec * 32 + q4 * 8]);
            const int rb0 = (KK == 3) ? (wt * 64 + r + sec - pl + HALO) : (wt * 64 + r);
            const int cb0 = (KK == 3) ? 0 : sec * 32;
#pragma unroll
            for (int jt = 0; jt < 4; ++jt)
                bf[jt] = *reinterpret_cast<const h8*>(&sB[(rb0 + jt * 16) * BST + cb0 + q4 * 8]);
#pragma unroll
            for (int im = 0; im < 4; ++im)
#pragma unroll
                for (int jt = 0; jt < 4; ++jt)
                    acc[im][jt] = __builtin_amdgcn_mfma_f32_16x16x32_f16(af[im], bf[jt], acc[im][jt], 0, 0, 0);
        }
    }
    // ---- epilogue: D row = m (q4*4+reg), col = t (r) ----
#pragma unroll
    for (int im = 0; im < 4; ++im) {
        const int mb = m0 + wm * 64 + im * 16 + q4 * 4;
        const float4 bv = *reinterpret_cast<const float4*>(&bias[mb]);
#pragma unroll
        for (int jt = 0; jt < 4; ++jt) {
            const int t = t0 + wt * 64 + jt * 16 + r;
            float vv[4];
            vv[0] = acc[im][jt][0] + bv.x;
            vv[1] = acc[im][jt][1] + bv.y;
            vv[2] = acc[im][jt][2] + bv.z;
            vv[3] = acc[im][jt][3] + bv.w;
            if (do_relu) {
#pragma unroll
                for (int c = 0; c < 4; ++c) vv[c] = fmaxf(vv[c], 0.f);
            }
            if (mask_out) {
                const float mv = mk[t];
#pragma unroll
                for (int c = 0; c < 4; ++c) vv[c] *= mv;
            }
            if (OUTMODE == 1) {
                const size_t ob = ((size_t)b * T_LEN + t) * out_stride + mb;
                if (res) {
                    const h4 rv = *reinterpret_cast<const h4*>(&res[ob]);
#pragma unroll
                    for (int c = 0; c < 4; ++c) vv[c] += (float)rv[c];
                }
                h4 hv;
#pragma unroll
                for (int c = 0; c < 4; ++c) hv[c] = (_Float16)vv[c];
                *reinterpret_cast<h4*>(&out_v[ob]) = hv;
            } else {   // fused QKV
                if (m0 < 1024) {
                    const size_t ob = ((size_t)b * T_LEN + t) * 1024 + mb;
                    h4 hv;
#pragma unroll
                    for (int c = 0; c < 4; ++c) hv[c] = (_Float16)vv[c];
                    *reinterpret_cast<h4*>(&out_v[ob]) = hv;
                } else {
#pragma unroll
                    for (int reg = 0; reg < 4; ++reg)
                        out2[((size_t)b * C_CH + (mb - 1024) + reg) * T_LEN + t] = (_Float16)vv[reg];
                }
            }
        }
    }
}

// ---------------------------------------------------------------------------
// MFMA flash attention with ONLINE softmax (p <= 1, f16-safe).
// qk: [b][t][1024] f16 (q|k); vt: [b][h*64+d][t] f16; o: [b][t][512] f16.
// Q-tile 128 (32 rows/wave), K-tile 64. blockIdx.x reversed: longest first.
// ---------------------------------------------------------------------------
__global__ __launch_bounds__(256)
void flash_attn_mfma(const _Float16* __restrict__ qk, const _Float16* __restrict__ vt,
                     _Float16* __restrict__ o)
{
    __shared__ _Float16 sK[64 * 72];    // [s][d]
    __shared__ _Float16 sVt[64 * 72];   // [d][s]
    __shared__ _Float16 sP[128 * 72];   // [q][s]
    const int tid = threadIdx.x;
    const int lane = tid & 63;
    const int w = tid >> 6;
    const int r = lane & 15, q4 = lane >> 4;
    const int qt0 = (int)(15 - blockIdx.x) * 128;
    const int h = blockIdx.y, b = blockIdx.z;
    const size_t tb = (size_t)b * T_LEN;
    const int hq = h * 64, hk = 512 + h * 64;
    const _Float16* vbase = vt + ((size_t)b * C_CH + h * 64) * T_LEN;

    h8 qf[2][2];
#pragma unroll
    for (int im = 0; im < 2; ++im)
#pragma unroll
        for (int dc = 0; dc < 2; ++dc) {
            h8 t = *reinterpret_cast<const h8*>(
                &qk[(tb + qt0 + w * 32 + im * 16 + r) * 1024 + hq + dc * 32 + q4 * 8]);
            qf[im][dc] = t * (_Float16)0.125f;
        }

    floatx4 oacc[2][4];
    float mrow[2][4], lrow[2][4];
#pragma unroll
    for (int im = 0; im < 2; ++im)
#pragma unroll
        for (int reg = 0; reg < 4; ++reg) {
            mrow[im][reg] = -__builtin_inff();
            lrow[im][reg] = 0.f;
        }
#pragma unroll
    for (int im = 0; im < 2; ++im)
#pragma unroll
        for (int jd = 0; jd < 4; ++jd)
#pragma unroll
            for (int c = 0; c < 4; ++c) oacc[im][jd][c] = 0.f;

    const int qhi = qt0 + w * 32 + 31;
    const int nk = (qt0 >> 6) + 2;
    for (int kt = 0; kt < nk; ++kt) {
        const int kt0 = kt * 64;
        __syncthreads();
        {
            int row = tid >> 2, c16 = (tid & 3) * 16;
            const _Float16* src = &qk[(tb + kt0 + row) * 1024 + hk + c16];
            *reinterpret_cast<h8*>(&sK[row * 72 + c16]) = *reinterpret_cast<const h8*>(src);
            *reinterpret_cast<h8*>(&sK[row * 72 + c16 + 8]) = *reinterpret_cast<const h8*>(src + 8);
        }
#pragma unroll
        for (int p = 0; p < 2; ++p) {
            int id = p * 256 + tid;
            int d = id >> 3, s8 = (id & 7) * 8;
            *reinterpret_cast<h8*>(&sVt[d * 72 + s8]) =
                *reinterpret_cast<const h8*>(&vbase[(size_t)d * T_LEN + kt0 + s8]);
        }
        __syncthreads();
        if (kt0 <= qhi) {
            floatx4 sacc[2][4];
#pragma unroll
            for (int im = 0; im < 2; ++im)
#pragma unroll
                for (int js = 0; js < 4; ++js)
#pragma unroll
                    for (int c = 0; c < 4; ++c) sacc[im][js][c] = 0.f;
#pragma unroll
            for (int dc = 0; dc < 2; ++dc) {
                h8 kf[4];
#pragma unroll
                for (int js = 0; js < 4; ++js)
                    kf[js] = *reinterpret_cast<const h8*>(&sK[(js * 16 + r) * 72 + dc * 32 + q4 * 8]);
#pragma unroll
                for (int im = 0; im < 2; ++im)
#pragma unroll
                    for (int js = 0; js < 4; ++js)
                        sacc[im][js] = __builtin_amdgcn_mfma_f32_16x16x32_f16(qf[im][dc], kf[js], sacc[im][js], 0, 0, 0);
            }
#pragma unroll
            for (int im = 0; im < 2; ++im)
#pragma unroll
                for (int js = 0; js < 4; ++js) {
                    const int s_g = kt0 + js * 16 + r;
#pragma unroll
                    for (int reg = 0; reg < 4; ++reg) {
                        const int q_g = qt0 + w * 32 + im * 16 + q4 * 4 + reg;
                        if (s_g > q_g) sacc[im][js][reg] = -1e4f;
                    }
                }
            float mt[2][4];
#pragma unroll
            for (int im = 0; im < 2; ++im)
#pragma unroll
                for (int reg = 0; reg < 4; ++reg) {
                    float m0v = fmaxf(fmaxf(sacc[im][0][reg], sacc[im][1][reg]),
                                      fmaxf(sacc[im][2][reg], sacc[im][3][reg]));
#pragma unroll
                    for (int off = 1; off < 16; off <<= 1)
                        m0v = fmaxf(m0v, __shfl_xor(m0v, off));
                    mt[im][reg] = m0v;
                }
            float alpha[2][4];
#pragma unroll
            for (int im = 0; im < 2; ++im)
#pragma unroll
                for (int reg = 0; reg < 4; ++reg) {
                    float mn = fmaxf(mrow[im][reg], mt[im][reg]);
                    alpha[im][reg] = __expf(mrow[im][reg] - mn);
                    mrow[im][reg] = mn;
                    float rs = 0.f;
#pragma unroll
                    for (int js = 0; js < 4; ++js) {
                        float p = __expf(sacc[im][js][reg] - mn);
                        sacc[im][js][reg] = p;
                        rs += p;
                    }
#pragma unroll
                    for (int off = 1; off < 16; off <<= 1)
                        rs += __shfl_xor(rs, off);
                    lrow[im][reg] = lrow[im][reg] * alpha[im][reg] + rs;
                }
#pragma unroll
            for (int im = 0; im < 2; ++im)
#pragma unroll
                for (int jd = 0; jd < 4; ++jd)
#pragma unroll
                    for (int reg = 0; reg < 4; ++reg)
                        oacc[im][jd][reg] *= alpha[im][reg];
#pragma unroll
            for (int im = 0; im < 2; ++im)
#pragma unroll
                for (int js = 0; js < 4; ++js)
#pragma unroll
                    for (int reg = 0; reg < 4; ++reg)
                        sP[(w * 32 + im * 16 + q4 * 4 + reg) * 72 + js * 16 + r] =
                            (_Float16)sacc[im][js][reg];
#pragma unroll
            for (int sc = 0; sc < 2; ++sc) {
                h8 pf[2], vf[4];
#pragma unroll
                for (int im = 0; im < 2; ++im)
                    pf[im] = *reinterpret_cast<const h8*>(&sP[(w * 32 + im * 16 + r) * 72 + sc * 32 + q4 * 8]);
#pragma unroll
                for (int jd = 0; jd < 4; ++jd)
                    vf[jd] = *reinterpret_cast<const h8*>(&sVt[(jd * 16 + r) * 72 + sc * 32 + q4 * 8]);
#pragma unroll
                for (int im = 0; im < 2; ++im)
#pragma unroll
                    for (int jd = 0; jd < 4; ++jd)
                        oacc[im][jd] = __builtin_amdgcn_mfma_f32_16x16x32_f16(pf[im], vf[jd], oacc[im][jd], 0, 0, 0);
            }
        }
    }
#pragma unroll
    for (int im = 0; im < 2; ++im)
#pragma unroll
        for (int reg = 0; reg < 4; ++reg) {
            const float inv = 1.f / lrow[im][reg];
            const size_t rowb = (tb + qt0 + w * 32 + im * 16 + q4 * 4 + reg) * 512 + h * 64 + r;
#pragma unroll
            for (int jd = 0; jd < 4; ++jd)
                o[rowb + jd * 16] = (_Float16)(oacc[im][jd][reg] * inv);
        }
}

// ---------------------------------------------------------------------------
// Channel LayerNorm on f16 [b][t][512]: one wave per t-row. outx = LN(x+y)*g+be
// ---------------------------------------------------------------------------
__global__ __launch_bounds__(256)
void ln_kernel(const _Float16* __restrict__ x, const _Float16* __restrict__ y,
               const float* __restrict__ g, const float* __restrict__ be,
               _Float16* __restrict__ outx)
{
    const int w = threadIdx.x >> 6, lane = threadIdx.x & 63;
    const int t = blockIdx.x * 4 + w, b = blockIdx.y;
    const size_t base = ((size_t)b * T_LEN + t) * C_CH + lane * 8;
    h8 xv = *reinterpret_cast<const h8*>(&x[base]);
    h8 yv = *reinterpret_cast<const h8*>(&y[base]);
    float v[8];
#pragma unroll
    for (int i = 0; i < 8; ++i) v[i] = (float)xv[i] + (float)yv[i];
    float s = 0.f, s2 = 0.f;
#pragma unroll
    for (int i = 0; i < 8; ++i) { s += v[i]; s2 += v[i] * v[i]; }
#pragma unroll
    for (int off = 1; off < 64; off <<= 1) {
        s  += __shfl_xor(s, off);
        s2 += __shfl_xor(s2, off);
    }
    const float mean = s * (1.f / C_CH);
    const float var  = s2 * (1.f / C_CH) - mean * mean;
    const float rstd = rsqrtf(var + 1e-5f);
    float4 g0 = *reinterpret_cast<const float4*>(&g[lane * 8]);
    float4 g1 = *reinterpret_cast<const float4*>(&g[lane * 8 + 4]);
    float4 b0 = *reinterpret_cast<const float4*>(&be[lane * 8]);
    float4 b1 = *reinterpret_cast<const float4*>(&be[lane * 8 + 4]);
    const float gg[8] = {g0.x, g0.y, g0.z, g0.w, g1.x, g1.y, g1.z, g1.w};
    const float bb[8] = {b0.x, b0.y, b0.z, b0.w, b1.x, b1.y, b1.z, b1.w};
    h8 ov;
#pragma unroll
    for (int i = 0; i < 8; ++i)
        ov[i] = (_Float16)((v[i] - mean) * rstd * gg[i] + bb[i]);
    *reinterpret_cast<h8*>(&outx[base]) = ov;
}

// out[b,t] = ( mask * sum_c pw[c]*x[b,t,c] + pb ) * mask   (one wave per t)
__global__ __launch_bounds__(256)
void proj_kernel(const _Float16* __restrict__ x, const float* __restrict__ pw,
                 const float* __restrict__ pb, const float* __restrict__ mask,
                 float* __restrict__ out)
{
    const int w = threadIdx.x >> 6, lane = threadIdx.x & 63;
    const int t = blockIdx.x * 4 + w, b = blockIdx.y;
    const size_t base = ((size_t)b * T_LEN + t) * C_CH + lane * 8;
    h8 xv = *reinterpret_cast<const h8*>(&x[base]);
    float4 p0 = *reinterpret_cast<const float4*>(&pw[lane * 8]);
    float4 p1 = *reinterpret_cast<const float4*>(&pw[lane * 8 + 4]);
    const float pp[8] = {p0.x, p0.y, p0.z, p0.w, p1.x, p1.y, p1.z, p1.w};
    float s = 0.f;
#pragma unroll
    for (int i = 0; i < 8; ++i) s += (float)xv[i] * pp[i];
#pragma unroll
    for (int off = 1; off < 64; off <<= 1) s += __shfl_xor(s, off);
    if (lane == 0) {
        const float mv = mask[(size_t)b * T_LEN + t];
        out[(size_t)b * T_LEN + t] = (s * mv + pb[0]) * mv;
    }
}

extern "C" void kernel_launch(void* const* d_in, const int* in_sizes, int n_in,
                              void* d_out, int out_size, void* d_ws, size_t ws_size,
                              hipStream_t stream)
{
    const float* x    = (const float*)d_in[0];
    const float* nf0  = (const float*)d_in[1];
    const float* xm   = (const float*)d_in[2];
    const float* spk  = (const float*)d_in[3];
    const float* prw  = (const float*)d_in[4];
    const float* prb  = (const float*)d_in[5];
    const float* f0w  = (const float*)d_in[6];
    const float* f0b  = (const float*)d_in[7];
    const float* cw   = (const float*)d_in[8];
    const float* cb   = (const float*)d_in[9];
    const float* pjw  = (const float*)d_in[10];
    const float* pjb  = (const float*)d_in[11];
    const float* qw   = (const float*)d_in[12];
    const float* qb   = (const float*)d_in[13];
    const float* kw   = (const float*)d_in[14];
    const float* kb   = (const float*)d_in[15];
    const float* vw   = (const float*)d_in[16];
    const float* vb   = (const float*)d_in[17];
    const float* ow   = (const float*)d_in[18];
    const float* ob   = (const float*)d_in[19];
    const float* ln0g = (const float*)d_in[20];
    const float* ln0b = (const float*)d_in[21];
    const float* ln1g = (const float*)d_in[22];
    const float* ln1b = (const float*)d_in[23];
    const float* f1w  = (const float*)d_in[24];
    const float* f1b  = (const float*)d_in[25];
    const float* f2w  = (const float*)d_in[26];
    const float* f2b  = (const float*)d_in[27];
    float* out = (float*)d_out;

    const size_t NCT = (size_t)B_SZ * C_CH * T_LEN;
    char* wp = (char*)d_ws;
    _Float16* xbuf = (_Float16*)wp; wp += NCT * 2;            // [b][t][512] residual
    _Float16* t0h  = (_Float16*)wp; wp += NCT * 2;            // [b][t][512] sublayer out
    _Float16* qk   = (_Float16*)wp; wp += NCT * 4;            // [b][t][1024]
    _Float16* vt   = (_Float16*)wp; wp += NCT * 2;            // [b][h*64+d][t]
    _Float16* obf  = (_Float16*)wp; wp += NCT * 2;            // [b][t][512]
    _Float16* h1   = (_Float16*)wp; wp += NCT * 8;            // [b][t][2048]
    _Float16* xT   = h1;                                       // alias (dead before h1 use)
    _Float16* spkT = obf;                                      // alias (dead before obf use)
    _Float16* Wqkv = (_Float16*)wp; wp += (size_t)L_N * 1536 * 512 * 2;
    _Float16* Wo   = (_Float16*)wp; wp += (size_t)L_N * 512 * 512 * 2;
    _Float16* Wcnd = (_Float16*)wp; wp += (size_t)512 * 256 * 2;
    _Float16* Wpre = (_Float16*)wp; wp += (size_t)512 * 512 * 3 * 2;
    _Float16* Wf1  = (_Float16*)wp; wp += (size_t)L_N * 2048 * 512 * 3 * 2;
    _Float16* Wf2  = (_Float16*)wp; wp += (size_t)L_N * 512 * 2048 * 3 * 2;
    float*    Bqkv = (float*)wp;    wp += (size_t)L_N * 1536 * 4;

    dim3 blk(256);
    dim3 gC(16, 4, B_SZ);       // M=512 convs
    dim3 gQKV(16, 12, B_SZ);    // M=1536 fused QKV
    dim3 gF(16, 16, B_SZ);      // M=2048 ffn1
    dim3 gAT(16, H_N, B_SZ);    // flash
    dim3 gLN(T_LEN / 4, B_SZ);

    // ---- weight prepack ----
    {
        int n;
        n = C_CH * S_CH;            cast_f16<<<(n + 255) / 256, blk, 0, stream>>>(cw, Wcnd, n);
        n = L_N * C_CH * C_CH;      cast_f16<<<(n + 255) / 256, blk, 0, stream>>>(ow, Wo, n);
        n = C_CH * C_CH * 3;        prepack_k3<<<(n + 255) / 256, blk, 0, stream>>>(prw, Wpre, C_CH, n);
        n = L_N * FC_CH * C_CH * 3; prepack_k3<<<(n + 255) / 256, blk, 0, stream>>>(f1w, Wf1, C_CH, n);
        n = L_N * C_CH * FC_CH * 3; prepack_k3<<<(n + 255) / 256, blk, 0, stream>>>(f2w, Wf2, FC_CH, n);
        n = L_N * 1536 * 512;       prepack_qkv<<<(n + 255) / 256, blk, 0, stream>>>(qw, kw, vw, qb, kb, vb, Wqkv, Bqkv);
    }

    // ---- prologue ----
    transpose_f0<<<dim3(64, 16, B_SZ), blk, 0, stream>>>(x, xT, C_CH, nf0, f0w, f0b, 1);
    transpose_f0<<<dim3(64, 8, B_SZ), blk, 0, stream>>>(spk, spkT, S_CH, nullptr, nullptr, nullptr, 0);
    conv_gemm_mfma<1, 1><<<gC, blk, 0, stream>>>(spkT, Wcnd, cb, xT, xm, t0h, nullptr, S_CH, C_CH, 0, 0, 0, 0);
    conv_gemm_mfma<3, 1><<<gC, blk, 0, stream>>>(t0h, Wpre, prb, nullptr, xm, xbuf, nullptr, C_CH, C_CH, 1, 0, 0, 1);

    for (int l = 0; l < L_N; ++l) {
        const size_t bo = (size_t)l * C_CH;
        conv_gemm_mfma<1, 3><<<gQKV, blk, 0, stream>>>(xbuf, Wqkv + (size_t)l * 1536 * 512, Bqkv + l * 1536,
                                                       nullptr, xm, qk, vt, C_CH, 1024, 0, 0, 0, 0);
        flash_attn_mfma<<<gAT, blk, 0, stream>>>(qk, vt, obf);
        conv_gemm_mfma<1, 1><<<gC, blk, 0, stream>>>(obf, Wo + (size_t)l * 512 * 512, ob + bo,
                                                     nullptr, xm, t0h, nullptr, C_CH, C_CH, 0, 0, 0, 0);
        ln_kernel<<<gLN, blk, 0, stream>>>(xbuf, t0h, ln0g + bo, ln0b + bo, xbuf);
        conv_gemm_mfma<3, 1><<<gF, blk, 0, stream>>>(xbuf, Wf1 + (size_t)l * FC_CH * C_CH * 3, f1b + (size_t)l * FC_CH,
                                                     nullptr, xm, h1, nullptr, C_CH, FC_CH, 2, 1, 1, 0);
        conv_gemm_mfma<3, 1><<<gC, blk, 0, stream>>>(h1, Wf2 + (size_t)l * C_CH * FC_CH * 3, f2b + bo,
                                                     nullptr, xm, t0h, nullptr, FC_CH, C_CH, 2, 0, 1, 1);
        ln_kernel<<<gLN, blk, 0, stream>>>(xbuf, t0h, ln1g + bo, ln1b + bo, xbuf);
    }
    proj_kernel<<<gLN, blk, 0, stream>>>(xbuf, pjw, pjb, xm, out);
}

// Round 8
// 2485.609 us; speedup vs baseline: 9.9944x; 9.9944x over previous
//
#include <hip/hip_runtime.h>
#include <cstdint>
#include <cstddef>

#define T_LEN 2048
#define B_SZ 4
#define C_CH 512
#define H_N 8
#define DK_ 64
#define FC_CH 2048
#define L_N 6
#define KW 3
#define S_CH 256

typedef _Float16 h8 __attribute__((ext_vector_type(8)));
typedef _Float16 h4 __attribute__((ext_vector_type(4)));
typedef float floatx4 __attribute__((ext_vector_type(4)));

// ---------------------------------------------------------------------------
// Weight prepack kernels (run every call; weights -> f16 in ws).
// ---------------------------------------------------------------------------
__global__ __launch_bounds__(256)
void cast_f16(const float* __restrict__ src, _Float16* __restrict__ dst, int n)
{
    int i = blockIdx.x * 256 + threadIdx.x;
    if (i < n) dst[i] = (_Float16)src[i];
}

// src [row][c][k] (k fastest, K=3) -> dst [row][c0blk][k][cl] (32-ch chunks)
__global__ __launch_bounds__(256)
void prepack_k3(const float* __restrict__ src, _Float16* __restrict__ dst,
                int Cin, int total)
{
    int i = blockIdx.x * 256 + threadIdx.x;
    if (i >= total) return;
    const int rk = Cin * 3;
    int row = i / rk, o = i - row * rk;
    int blk = o / 96, rr = o - blk * 96;
    int k = rr >> 5, cl = rr & 31;
    dst[i] = (_Float16)src[(size_t)row * rk + (size_t)(blk * 32 + cl) * 3 + k];
}

// concat q|k|v weights into [l][1536][512] f16 + biases into [l][1536] f32
__global__ __launch_bounds__(256)
void prepack_qkv(const float* __restrict__ qw, const float* __restrict__ kw,
                 const float* __restrict__ vw, const float* __restrict__ qb,
                 const float* __restrict__ kb, const float* __restrict__ vb,
                 _Float16* __restrict__ dst, float* __restrict__ bdst)
{
    int i = blockIdx.x * 256 + threadIdx.x;
    const int total = L_N * 1536 * 512;
    if (i < total) {
        int l = i / (1536 * 512);
        int o = i - l * (1536 * 512);
        int m = o >> 9, c = o & 511;
        const float* s = (m < 512) ? qw : ((m < 1024) ? kw : vw);
        dst[i] = (_Float16)s[((size_t)l * 512 + (m & 511)) * 512 + c];
    }
    if (i < L_N * 1536) {
        int l = i / 1536, m = i - l * 1536;
        const float* s = (m < 512) ? qb : ((m < 1024) ? kb : vb);
        bdst[i] = s[l * 512 + (m & 511)];
    }
}

// ---------------------------------------------------------------------------
// Transpose [b][Cd][T] -> f16 [b][T][Cd], optionally fusing the f0 conv add.
// ---------------------------------------------------------------------------
__global__ __launch_bounds__(256)
void transpose_f0(const float* __restrict__ src, _Float16* __restrict__ dst, int Cd,
                  const float* __restrict__ nf0, const float* __restrict__ f0w,
                  const float* __restrict__ f0b, int do_f0)
{
    __shared__ float tile[32][33];
    const int tl = threadIdx.x & 31;
    const int r  = threadIdx.x >> 5;
    const int t00 = blockIdx.x * 32;
    const int c00 = blockIdx.y * 32;
    const int b   = blockIdx.z;
    const float* s0 = src + (size_t)b * Cd * T_LEN;
#pragma unroll
    for (int rr = 0; rr < 4; ++rr) {
        int cl = r + rr * 8;
        tile[cl][tl] = s0[(size_t)(c00 + cl) * T_LEN + t00 + tl];
    }
    __syncthreads();
    _Float16* d0 = dst + (size_t)b * T_LEN * Cd;
    const int cg = c00 + tl;
#pragma unroll
    for (int rr = 0; rr < 4; ++rr) {
        int tlo = r + rr * 8;
        float v = tile[tl][tlo];
        if (do_f0) {
            int tg = t00 + tlo;
            float a = f0b[cg];
#pragma unroll
            for (int k = 0; k < 3; ++k) {
                int gt = tg + k - 1;
                if (gt >= 0 && gt < T_LEN) a += f0w[cg * 3 + k] * nf0[(size_t)b * T_LEN + gt];
            }
            v += a;
        }
        d0[(size_t)(t00 + tlo) * Cd + cg] = (_Float16)v;
    }
}

// ---------------------------------------------------------------------------
// Conv1d-as-GEMM on MFMA, prepacked f16 weights, f16 activations.
// Pipelining: A 1-deep register prefetch; B 2-deep register double-buffer.
// CRITICAL (round-7 lesson): buffer selection must be COMPILE-TIME — the chunk
// loop advances by 2 with two statically-named buffers (breg0/breg1). A
// runtime-indexed register array (breg[ci&1]) demotes to scratch memory and
// costs ~13x. All conv call sites have even nch = Cin/CS (4/8/16/64).
// LDS staging write patterns are bank-conflict-free (KK=3: A row=tid&127
// @52-word stride; B row=id%132 @20-word stride; KK=1 @36-word stride).
// OUTMODE: 1 = f16 [b][t][out_stride] (+res); 3 = fused QKV (m0<1024 -> out_v
// stride 1024; m0>=1024 -> out2 transposed [b][m-1024][t]).
// ---------------------------------------------------------------------------
template<int KK, int OUTMODE>
__global__ __launch_bounds__(256)
void conv_gemm_mfma(const _Float16* __restrict__ in, const _Float16* __restrict__ Wpk,
                    const float* __restrict__ bias, const _Float16* __restrict__ res,
                    const float* __restrict__ mask, _Float16* __restrict__ out_v,
                    _Float16* __restrict__ out2,
                    int Cin, int out_stride, int pl, int do_relu,
                    int mask_in, int mask_out)
{
    constexpr int CS   = (KK == 3) ? 32 : 64;   // channels per chunk
    constexpr int NSEC = (KK == 3) ? 3 : 2;     // 32-wide A sections
    constexpr int AST  = NSEC * 32 + 8;         // 104 / 72 halves
    constexpr int HALO = (KK == 3) ? 2 : 0;
    constexpr int RB   = 128 + 2 * HALO;
    constexpr int BST  = CS + 8;                // 40 / 72 halves
    constexpr int NAH  = NSEC * 2;              // A h8-regs per thread
    constexpr int NTASK = RB * (CS / 16);       // B 16-half tasks (264 / 512)
    __shared__ _Float16 sA[128 * AST];
    __shared__ _Float16 sB[RB * BST];

    const int tid = threadIdx.x;
    const int lane = tid & 63;
    const int wid = tid >> 6;
    const int wm = wid >> 1, wt = wid & 1;
    const int r = lane & 15, q4 = lane >> 4;
    const int t0 = blockIdx.x * 128;
    const int m0 = blockIdx.y * 128;
    const int b  = blockIdx.z;
    const float* mk = mask + (size_t)b * T_LEN;

    floatx4 acc[4][4];
#pragma unroll
    for (int i = 0; i < 4; ++i)
#pragma unroll
        for (int j = 0; j < 4; ++j)
#pragma unroll
            for (int c = 0; c < 4; ++c) acc[i][j][c] = 0.f;

    // ---- A staging assignment (bank-conflict-free writes) ----
    const int arow = (KK == 3) ? (tid & 127) : (tid >> 1);
    const int ah0  = (KK == 3) ? ((tid >> 7) * (NSEC * 16)) : ((tid & 1) * (NSEC * 16));
    const _Float16* ap = Wpk + (size_t)(m0 + arow) * Cin * KK + ah0;

    // ---- B task decode (chunk-invariant) ----
    int brw[2], bcc[2];
    bool bex[2], bval[2];
    _Float16 bm[2];
    const _Float16* bq[2];
    h8 areg[NAH], breg0[2][2], breg1[2][2];   // [task][half], buffers statically named
#pragma unroll
    for (int t2 = 0; t2 < 2; ++t2) {
        const int id = tid + t2 * 256;
        bex[t2] = (id < NTASK);
        int row, c16;
        if (KK == 3) { row = id % RB; c16 = (id / RB) * 16; }
        else         { row = id >> 2; c16 = (id & 3) * 16; }
        const int gt = t0 + row - HALO;
        bval[t2] = bex[t2] && gt >= 0 && gt < T_LEN;
        brw[t2] = row; bcc[t2] = c16;
        bm[t2] = (_Float16)((bval[t2] && mask_in) ? mk[gt] : 1.f);
        bq[t2] = in + (size_t)b * T_LEN * Cin + (size_t)gt * Cin + c16;
#pragma unroll
        for (int hh = 0; hh < 2; ++hh)
#pragma unroll
            for (int j = 0; j < 8; ++j) {
                breg0[t2][hh][j] = (_Float16)0.f;
                breg1[t2][hh][j] = (_Float16)0.f;
            }
    }
    const int nch = Cin / CS;   // even for all call sites
    // ---- prologue: A chunk 0; B chunks 0 (breg0) and 1 (breg1) ----
#pragma unroll
    for (int j = 0; j < NAH; ++j) areg[j] = *reinterpret_cast<const h8*>(ap + j * 8);
#pragma unroll
    for (int t2 = 0; t2 < 2; ++t2)
        if (bval[t2]) {
            breg0[t2][0] = *reinterpret_cast<const h8*>(bq[t2]);
            breg0[t2][1] = *reinterpret_cast<const h8*>(bq[t2] + 8);
            breg1[t2][0] = *reinterpret_cast<const h8*>(bq[t2] + CS);
            breg1[t2][1] = *reinterpret_cast<const h8*>(bq[t2] + CS + 8);
            bq[t2] += 2 * CS;
        }

    // one chunk: stage LDS from br, prefetch A(ci+1) + B(ci+2)->br, run MFMAs.
    auto run_chunk = [&](h8 (&br)[2][2], int ci) {
        __syncthreads();
#pragma unroll
        for (int j = 0; j < NAH; ++j)
            *reinterpret_cast<h8*>(&sA[arow * AST + ah0 + j * 8]) = areg[j];
#pragma unroll
        for (int t2 = 0; t2 < 2; ++t2)
            if (bex[t2]) {
                *reinterpret_cast<h8*>(&sB[brw[t2] * BST + bcc[t2]]) = br[t2][0] * bm[t2];
                *reinterpret_cast<h8*>(&sB[brw[t2] * BST + bcc[t2] + 8]) = br[t2][1] * bm[t2];
            }
        __syncthreads();
        if (ci + 1 < nch) {
            ap += CS * KK;
#pragma unroll
            for (int j = 0; j < NAH; ++j) areg[j] = *reinterpret_cast<const h8*>(ap + j * 8);
        }
        if (ci + 2 < nch) {
#pragma unroll
            for (int t2 = 0; t2 < 2; ++t2)
                if (bval[t2]) {
                    br[t2][0] = *reinterpret_cast<const h8*>(bq[t2]);
                    br[t2][1] = *reinterpret_cast<const h8*>(bq[t2] + 8);
                    bq[t2] += CS;
                }
        }
#pragma unroll
        for (int sec = 0; sec < NSEC; ++sec) {
            h8 af[4], bf[4];
#pragma unroll
            for (int im = 0; im < 4; ++im)
                af[im] = *reinterpret_cast<const h8*>(&sA[(wm * 64 + im * 16 + r) * AST + sec * 32 + q4 * 8]);
            const int rb0 = (KK == 3) ? (wt * 64 + r + sec - pl + HALO) : (wt * 64 + r);
            const int cb0 = (KK == 3) ? 0 : sec * 32;
#pragma unroll
            for (int jt = 0; jt < 4; ++jt)
                bf[jt] = *reinterpret_cast<const h8*>(&sB[(rb0 + jt * 16) * BST + cb0 + q4 * 8]);
#pragma unroll
            for (int im = 0; im < 4; ++im)
#pragma unroll
                for (int jt = 0; jt < 4; ++jt)
                    acc[im][jt] = __builtin_amdgcn_mfma_f32_16x16x32_f16(af[im], bf[jt], acc[im][jt], 0, 0, 0);
        }
    };

    for (int ci = 0; ci < nch; ci += 2) {
        run_chunk(breg0, ci);        // even chunk — static buffer
        run_chunk(breg1, ci + 1);    // odd chunk — static buffer
    }

    // ---- epilogue: D row = m (q4*4+reg), col = t (r) ----
#pragma unroll
    for (int im = 0; im < 4; ++im) {
        const int mb = m0 + wm * 64 + im * 16 + q4 * 4;
        const float4 bv = *reinterpret_cast<const float4*>(&bias[mb]);
#pragma unroll
        for (int jt = 0; jt < 4; ++jt) {
            const int t = t0 + wt * 64 + jt * 16 + r;
            float vv[4];
            vv[0] = acc[im][jt][0] + bv.x;
            vv[1] = acc[im][jt][1] + bv.y;
            vv[2] = acc[im][jt][2] + bv.z;
            vv[3] = acc[im][jt][3] + bv.w;
            if (do_relu) {
#pragma unroll
                for (int c = 0; c < 4; ++c) vv[c] = fmaxf(vv[c], 0.f);
            }
            if (mask_out) {
                const float mv = mk[t];
#pragma unroll
                for (int c = 0; c < 4; ++c) vv[c] *= mv;
            }
            if (OUTMODE == 1) {
                const size_t ob = ((size_t)b * T_LEN + t) * out_stride + mb;
                if (res) {
                    const h4 rv = *reinterpret_cast<const h4*>(&res[ob]);
#pragma unroll
                    for (int c = 0; c < 4; ++c) vv[c] += (float)rv[c];
                }
                h4 hv;
#pragma unroll
                for (int c = 0; c < 4; ++c) hv[c] = (_Float16)vv[c];
                *reinterpret_cast<h4*>(&out_v[ob]) = hv;
            } else {   // fused QKV
                if (m0 < 1024) {
                    const size_t ob = ((size_t)b * T_LEN + t) * 1024 + mb;
                    h4 hv;
#pragma unroll
                    for (int c = 0; c < 4; ++c) hv[c] = (_Float16)vv[c];
                    *reinterpret_cast<h4*>(&out_v[ob]) = hv;
                } else {
#pragma unroll
                    for (int reg = 0; reg < 4; ++reg)
                        out2[((size_t)b * C_CH + (mb - 1024) + reg) * T_LEN + t] = (_Float16)vv[reg];
                }
            }
        }
    }
}

// ---------------------------------------------------------------------------
// MFMA flash attention with ONLINE softmax (p <= 1, f16-safe).
// qk: [b][t][1024] f16 (q|k); vt: [b][h*64+d][t] f16; o: [b][t][512] f16.
// Q-tile 128 (32 rows/wave), K-tile 64. blockIdx.x reversed: longest first.
// ---------------------------------------------------------------------------
__global__ __launch_bounds__(256)
void flash_attn_mfma(const _Float16* __restrict__ qk, const _Float16* __restrict__ vt,
                     _Float16* __restrict__ o)
{
    __shared__ _Float16 sK[64 * 72];    // [s][d]
    __shared__ _Float16 sVt[64 * 72];   // [d][s]
    __shared__ _Float16 sP[128 * 72];   // [q][s]
    const int tid = threadIdx.x;
    const int lane = tid & 63;
    const int w = tid >> 6;
    const int r = lane & 15, q4 = lane >> 4;
    const int qt0 = (int)(15 - blockIdx.x) * 128;
    const int h = blockIdx.y, b = blockIdx.z;
    const size_t tb = (size_t)b * T_LEN;
    const int hq = h * 64, hk = 512 + h * 64;
    const _Float16* vbase = vt + ((size_t)b * C_CH + h * 64) * T_LEN;

    h8 qf[2][2];
#pragma unroll
    for (int im = 0; im < 2; ++im)
#pragma unroll
        for (int dc = 0; dc < 2; ++dc) {
            h8 t = *reinterpret_cast<const h8*>(
                &qk[(tb + qt0 + w * 32 + im * 16 + r) * 1024 + hq + dc * 32 + q4 * 8]);
            qf[im][dc] = t * (_Float16)0.125f;
        }

    floatx4 oacc[2][4];
    float mrow[2][4], lrow[2][4];
#pragma unroll
    for (int im = 0; im < 2; ++im)
#pragma unroll
        for (int reg = 0; reg < 4; ++reg) {
            mrow[im][reg] = -__builtin_inff();
            lrow[im][reg] = 0.f;
        }
#pragma unroll
    for (int im = 0; im < 2; ++im)
#pragma unroll
        for (int jd = 0; jd < 4; ++jd)
#pragma unroll
            for (int c = 0; c < 4; ++c) oacc[im][jd][c] = 0.f;

    const int qhi = qt0 + w * 32 + 31;
    const int nk = (qt0 >> 6) + 2;
    for (int kt = 0; kt < nk; ++kt) {
        const int kt0 = kt * 64;
        __syncthreads();
        {
            int row = tid >> 2, c16 = (tid & 3) * 16;
            const _Float16* src = &qk[(tb + kt0 + row) * 1024 + hk + c16];
            *reinterpret_cast<h8*>(&sK[row * 72 + c16]) = *reinterpret_cast<const h8*>(src);
            *reinterpret_cast<h8*>(&sK[row * 72 + c16 + 8]) = *reinterpret_cast<const h8*>(src + 8);
        }
#pragma unroll
        for (int p = 0; p < 2; ++p) {
            int id = p * 256 + tid;
            int d = id >> 3, s8 = (id & 7) * 8;
            *reinterpret_cast<h8*>(&sVt[d * 72 + s8]) =
                *reinterpret_cast<const h8*>(&vbase[(size_t)d * T_LEN + kt0 + s8]);
        }
        __syncthreads();
        if (kt0 <= qhi) {
            floatx4 sacc[2][4];
#pragma unroll
            for (int im = 0; im < 2; ++im)
#pragma unroll
                for (int js = 0; js < 4; ++js)
#pragma unroll
                    for (int c = 0; c < 4; ++c) sacc[im][js][c] = 0.f;
#pragma unroll
            for (int dc = 0; dc < 2; ++dc) {
                h8 kf[4];
#pragma unroll
                for (int js = 0; js < 4; ++js)
                    kf[js] = *reinterpret_cast<const h8*>(&sK[(js * 16 + r) * 72 + dc * 32 + q4 * 8]);
#pragma unroll
                for (int im = 0; im < 2; ++im)
#pragma unroll
                    for (int js = 0; js < 4; ++js)
                        sacc[im][js] = __builtin_amdgcn_mfma_f32_16x16x32_f16(qf[im][dc], kf[js], sacc[im][js], 0, 0, 0);
            }
#pragma unroll
            for (int im = 0; im < 2; ++im)
#pragma unroll
                for (int js = 0; js < 4; ++js) {
                    const int s_g = kt0 + js * 16 + r;
#pragma unroll
                    for (int reg = 0; reg < 4; ++reg) {
                        const int q_g = qt0 + w * 32 + im * 16 + q4 * 4 + reg;
                        if (s_g > q_g) sacc[im][js][reg] = -1e4f;
                    }
                }
            float mt[2][4];
#pragma unroll
            for (int im = 0; im < 2; ++im)
#pragma unroll
                for (int reg = 0; reg < 4; ++reg) {
                    float m0v = fmaxf(fmaxf(sacc[im][0][reg], sacc[im][1][reg]),
                                      fmaxf(sacc[im][2][reg], sacc[im][3][reg]));
#pragma unroll
                    for (int off = 1; off < 16; off <<= 1)
                        m0v = fmaxf(m0v, __shfl_xor(m0v, off));
                    mt[im][reg] = m0v;
                }
            float alpha[2][4];
#pragma unroll
            for (int im = 0; im < 2; ++im)
#pragma unroll
                for (int reg = 0; reg < 4; ++reg) {
                    float mn = fmaxf(mrow[im][reg], mt[im][reg]);
                    alpha[im][reg] = __expf(mrow[im][reg] - mn);
                    mrow[im][reg] = mn;
                    float rs = 0.f;
#pragma unroll
                    for (int js = 0; js < 4; ++js) {
                        float p = __expf(sacc[im][js][reg] - mn);
                        sacc[im][js][reg] = p;
                        rs += p;
                    }
#pragma unroll
                    for (int off = 1; off < 16; off <<= 1)
                        rs += __shfl_xor(rs, off);
                    lrow[im][reg] = lrow[im][reg] * alpha[im][reg] + rs;
                }
#pragma unroll
            for (int im = 0; im < 2; ++im)
#pragma unroll
                for (int jd = 0; jd < 4; ++jd)
#pragma unroll
                    for (int reg = 0; reg < 4; ++reg)
                        oacc[im][jd][reg] *= alpha[im][reg];
#pragma unroll
            for (int im = 0; im < 2; ++im)
#pragma unroll
                for (int js = 0; js < 4; ++js)
#pragma unroll
                    for (int reg = 0; reg < 4; ++reg)
                        sP[(w * 32 + im * 16 + q4 * 4 + reg) * 72 + js * 16 + r] =
                            (_Float16)sacc[im][js][reg];
#pragma unroll
            for (int sc = 0; sc < 2; ++sc) {
                h8 pf[2], vf[4];
#pragma unroll
                for (int im = 0; im < 2; ++im)
                    pf[im] = *reinterpret_cast<const h8*>(&sP[(w * 32 + im * 16 + r) * 72 + sc * 32 + q4 * 8]);
#pragma unroll
                for (int jd = 0; jd < 4; ++jd)
                    vf[jd] = *reinterpret_cast<const h8*>(&sVt[(jd * 16 + r) * 72 + sc * 32 + q4 * 8]);
#pragma unroll
                for (int im = 0; im < 2; ++im)
#pragma unroll
                    for (int jd = 0; jd < 4; ++jd)
                        oacc[im][jd] = __builtin_amdgcn_mfma_f32_16x16x32_f16(pf[im], vf[jd], oacc[im][jd], 0, 0, 0);
            }
        }
    }
#pragma unroll
    for (int im = 0; im < 2; ++im)
#pragma unroll
        for (int reg = 0; reg < 4; ++reg) {
            const float inv = 1.f / lrow[im][reg];
            const size_t rowb = (tb + qt0 + w * 32 + im * 16 + q4 * 4 + reg) * 512 + h * 64 + r;
#pragma unroll
            for (int jd = 0; jd < 4; ++jd)
                o[rowb + jd * 16] = (_Float16)(oacc[im][jd][reg] * inv);
        }
}

// ---------------------------------------------------------------------------
// Channel LayerNorm on f16 [b][t][512]: one wave per t-row. outx = LN(x+y)*g+be
// ---------------------------------------------------------------------------
__global__ __launch_bounds__(256)
void ln_kernel(const _Float16* __restrict__ x, const _Float16* __restrict__ y,
               const float* __restrict__ g, const float* __restrict__ be,
               _Float16* __restrict__ outx)
{
    const int w = threadIdx.x >> 6, lane = threadIdx.x & 63;
    const int t = blockIdx.x * 4 + w, b = blockIdx.y;
    const size_t base = ((size_t)b * T_LEN + t) * C_CH + lane * 8;
    h8 xv = *reinterpret_cast<const h8*>(&x[base]);
    h8 yv = *reinterpret_cast<const h8*>(&y[base]);
    float v[8];
#pragma unroll
    for (int i = 0; i < 8; ++i) v[i] = (float)xv[i] + (float)yv[i];
    float s = 0.f, s2 = 0.f;
#pragma unroll
    for (int i = 0; i < 8; ++i) { s += v[i]; s2 += v[i] * v[i]; }
#pragma unroll
    for (int off = 1; off < 64; off <<= 1) {
        s  += __shfl_xor(s, off);
        s2 += __shfl_xor(s2, off);
    }
    const float mean = s * (1.f / C_CH);
    const float var  = s2 * (1.f / C_CH) - mean * mean;
    const float rstd = rsqrtf(var + 1e-5f);
    float4 g0 = *reinterpret_cast<const float4*>(&g[lane * 8]);
    float4 g1 = *reinterpret_cast<const float4*>(&g[lane * 8 + 4]);
    float4 b0 = *reinterpret_cast<const float4*>(&be[lane * 8]);
    float4 b1 = *reinterpret_cast<const float4*>(&be[lane * 8 + 4]);
    const float gg[8] = {g0.x, g0.y, g0.z, g0.w, g1.x, g1.y, g1.z, g1.w};
    const float bb[8] = {b0.x, b0.y, b0.z, b0.w, b1.x, b1.y, b1.z, b1.w};
    h8 ov;
#pragma unroll
    for (int i = 0; i < 8; ++i)
        ov[i] = (_Float16)((v[i] - mean) * rstd * gg[i] + bb[i]);
    *reinterpret_cast<h8*>(&outx[base]) = ov;
}

// out[b,t] = ( mask * sum_c pw[c]*x[b,t,c] + pb ) * mask   (one wave per t)
__global__ __launch_bounds__(256)
void proj_kernel(const _Float16* __restrict__ x, const float* __restrict__ pw,
                 const float* __restrict__ pb, const float* __restrict__ mask,
                 float* __restrict__ out)
{
    const int w = threadIdx.x >> 6, lane = threadIdx.x & 63;
    const int t = blockIdx.x * 4 + w, b = blockIdx.y;
    const size_t base = ((size_t)b * T_LEN + t) * C_CH + lane * 8;
    h8 xv = *reinterpret_cast<const h8*>(&x[base]);
    float4 p0 = *reinterpret_cast<const float4*>(&pw[lane * 8]);
    float4 p1 = *reinterpret_cast<const float4*>(&pw[lane * 8 + 4]);
    const float pp[8] = {p0.x, p0.y, p0.z, p0.w, p1.x, p1.y, p1.z, p1.w};
    float s = 0.f;
#pragma unroll
    for (int i = 0; i < 8; ++i) s += (float)xv[i] * pp[i];
#pragma unroll
    for (int off = 1; off < 64; off <<= 1) s += __shfl_xor(s, off);
    if (lane == 0) {
        const float mv = mask[(size_t)b * T_LEN + t];
        out[(size_t)b * T_LEN + t] = (s * mv + pb[0]) * mv;
    }
}

extern "C" void kernel_launch(void* const* d_in, const int* in_sizes, int n_in,
                              void* d_out, int out_size, void* d_ws, size_t ws_size,
                              hipStream_t stream)
{
    const float* x    = (const float*)d_in[0];
    const float* nf0  = (const float*)d_in[1];
    const float* xm   = (const float*)d_in[2];
    const float* spk  = (const float*)d_in[3];
    const float* prw  = (const float*)d_in[4];
    const float* prb  = (const float*)d_in[5];
    const float* f0w  = (const float*)d_in[6];
    const float* f0b  = (const float*)d_in[7];
    const float* cw   = (const float*)d_in[8];
    const float* cb   = (const float*)d_in[9];
    const float* pjw  = (const float*)d_in[10];
    const float* pjb  = (const float*)d_in[11];
    const float* qw   = (const float*)d_in[12];
    const float* qb   = (const float*)d_in[13];
    const float* kw   = (const float*)d_in[14];
    const float* kb   = (const float*)d_in[15];
    const float* vw   = (const float*)d_in[16];
    const float* vb   = (const float*)d_in[17];
    const float* ow   = (const float*)d_in[18];
    const float* ob   = (const float*)d_in[19];
    const float* ln0g = (const float*)d_in[20];
    const float* ln0b = (const float*)d_in[21];
    const float* ln1g = (const float*)d_in[22];
    const float* ln1b = (const float*)d_in[23];
    const float* f1w  = (const float*)d_in[24];
    const float* f1b  = (const float*)d_in[25];
    const float* f2w  = (const float*)d_in[26];
    const float* f2b  = (const float*)d_in[27];
    float* out = (float*)d_out;

    const size_t NCT = (size_t)B_SZ * C_CH * T_LEN;
    char* wp = (char*)d_ws;
    _Float16* xbuf = (_Float16*)wp; wp += NCT * 2;            // [b][t][512] residual
    _Float16* t0h  = (_Float16*)wp; wp += NCT * 2;            // [b][t][512] sublayer out
    _Float16* qk   = (_Float16*)wp; wp += NCT * 4;            // [b][t][1024]
    _Float16* vt   = (_Float16*)wp; wp += NCT * 2;            // [b][h*64+d][t]
    _Float16* obf  = (_Float16*)wp; wp += NCT * 2;            // [b][t][512]
    _Float16* h1   = (_Float16*)wp; wp += NCT * 8;            // [b][t][2048]
    _Float16* xT   = h1;                                       // alias (dead before h1 use)
    _Float16* spkT = obf;                                      // alias (dead before obf use)
    _Float16* Wqkv = (_Float16*)wp; wp += (size_t)L_N * 1536 * 512 * 2;
    _Float16* Wo   = (_Float16*)wp; wp += (size_t)L_N * 512 * 512 * 2;
    _Float16* Wcnd = (_Float16*)wp; wp += (size_t)512 * 256 * 2;
    _Float16* Wpre = (_Float16*)wp; wp += (size_t)512 * 512 * 3 * 2;
    _Float16* Wf1  = (_Float16*)wp; wp += (size_t)L_N * 2048 * 512 * 3 * 2;
    _Float16* Wf2  = (_Float16*)wp; wp += (size_t)L_N * 512 * 2048 * 3 * 2;
    float*    Bqkv = (float*)wp;    wp += (size_t)L_N * 1536 * 4;

    dim3 blk(256);
    dim3 gC(16, 4, B_SZ);       // M=512 convs
    dim3 gQKV(16, 12, B_SZ);    // M=1536 fused QKV
    dim3 gF(16, 16, B_SZ);      // M=2048 ffn1
    dim3 gAT(16, H_N, B_SZ);    // flash
    dim3 gLN(T_LEN / 4, B_SZ);

    // ---- weight prepack ----
    {
        int n;
        n = C_CH * S_CH;            cast_f16<<<(n + 255) / 256, blk, 0, stream>>>(cw, Wcnd, n);
        n = L_N * C_CH * C_CH;      cast_f16<<<(n + 255) / 256, blk, 0, stream>>>(ow, Wo, n);
        n = C_CH * C_CH * 3;        prepack_k3<<<(n + 255) / 256, blk, 0, stream>>>(prw, Wpre, C_CH, n);
        n = L_N * FC_CH * C_CH * 3; prepack_k3<<<(n + 255) / 256, blk, 0, stream>>>(f1w, Wf1, C_CH, n);
        n = L_N * C_CH * FC_CH * 3; prepack_k3<<<(n + 255) / 256, blk, 0, stream>>>(f2w, Wf2, FC_CH, n);
        n = L_N * 1536 * 512;       prepack_qkv<<<(n + 255) / 256, blk, 0, stream>>>(qw, kw, vw, qb, kb, vb, Wqkv, Bqkv);
    }

    // ---- prologue ----
    transpose_f0<<<dim3(64, 16, B_SZ), blk, 0, stream>>>(x, xT, C_CH, nf0, f0w, f0b, 1);
    transpose_f0<<<dim3(64, 8, B_SZ), blk, 0, stream>>>(spk, spkT, S_CH, nullptr, nullptr, nullptr, 0);
    conv_gemm_mfma<1, 1><<<gC, blk, 0, stream>>>(spkT, Wcnd, cb, xT, xm, t0h, nullptr, S_CH, C_CH, 0, 0, 0, 0);
    conv_gemm_mfma<3, 1><<<gC, blk, 0, stream>>>(t0h, Wpre, prb, nullptr, xm, xbuf, nullptr, C_CH, C_CH, 1, 0, 0, 1);

    for (int l = 0; l < L_N; ++l) {
        const size_t bo = (size_t)l * C_CH;
        conv_gemm_mfma<1, 3><<<gQKV, blk, 0, stream>>>(xbuf, Wqkv + (size_t)l * 1536 * 512, Bqkv + l * 1536,
                                                       nullptr, xm, qk, vt, C_CH, 1024, 0, 0, 0, 0);
        flash_attn_mfma<<<gAT, blk, 0, stream>>>(qk, vt, obf);
        conv_gemm_mfma<1, 1><<<gC, blk, 0, stream>>>(obf, Wo + (size_t)l * 512 * 512, ob + bo,
                                                     nullptr, xm, t0h, nullptr, C_CH, C_CH, 0, 0, 0, 0);
        ln_kernel<<<gLN, blk, 0, stream>>>(xbuf, t0h, ln0g + bo, ln0b + bo, xbuf);
        conv_gemm_mfma<3, 1><<<gF, blk, 0, stream>>>(xbuf, Wf1 + (size_t)l * FC_CH * C_CH * 3, f1b + (size_t)l * FC_CH,
                                                     nullptr, xm, h1, nullptr, C_CH, FC_CH, 2, 1, 1, 0);
        conv_gemm_mfma<3, 1><<<gC, blk, 0, stream>>>(h1, Wf2 + (size_t)l * C_CH * FC_CH * 3, f2b + bo,
                                                     nullptr, xm, t0h, nullptr, FC_CH, C_CH, 2, 0, 1, 1);
        ln_kernel<<<gLN, blk, 0, stream>>>(xbuf, t0h, ln1g + bo, ln1b + bo, xbuf);
    }
    proj_kernel<<<gLN, blk, 0, stream>>>(xbuf, pjw, pjb, xm, out);
}